// Round 13
// baseline (83.909 us; speedup 1.0000x reference)
//
#include <hip/hip_runtime.h>
#include <math.h>

#define KC 32      // components
#define DD 256     // dims
#define QQ 16      // rank
#define NPTS 4096
#define NROW 16    // rows per main block
#define LOG2PI_F 1.8378770664093453f

typedef unsigned short ushort_t;

// ws layout (float offsets)
#define OFF_U    0      // [512] u2 = L^-1 (Lhat . mu)   (rotated)
#define OFF_LOGC 512    // [32]  log_pi - 0.5*(D*log2pi + logdetC + ck)
#define OFF_HB   544    // ushort [576][256] bf16 panel:
                        //   rows   0-511: Lhat2 = Psi^-1 Lam L^-T (comp k, rank q) at k*16+q
                        //   rows 512-543: V  = psi_inv (comp c at 512+c)
                        //   rows 544-575: W  = psi_inv*mu

__device__ __forceinline__ ushort_t f2bf(float f) {
    union { float f; unsigned int u; } c; c.f = f;
    unsigned int u = c.u;
    return (ushort_t)((u + 0x7FFFu + ((u >> 16) & 1u)) >> 16);   // RNE
}
__device__ __forceinline__ float bf2f(ushort_t h) {
    union { unsigned int u; float f; } c; c.u = ((unsigned int)h) << 16;
    return c.f;
}

using short8 = __attribute__((ext_vector_type(8))) short;   // 8 bf16 (4 VGPRs)
using f32x4  = __attribute__((ext_vector_type(4))) float;   // 4 fp32 acc

// ---------------- Kernel 1: per-component precompute (32 blocks x 256 thr) ----
// M,u via wave-0 MFMA; Cholesky M=LL^T; panel stores Lhat2 = Lhat L^-T, u2 = L^-1 u.
#define HSTR 264   // bf16 LDS row stride (ushorts)
__global__ __launch_bounds__(256) void precompute_kernel(
    const float* __restrict__ log_pi, const float* __restrict__ mu,
    const float* __restrict__ Lambda, const float* __restrict__ log_psi,
    float* __restrict__ ws)
{
    __shared__ __align__(16) ushort_t lamH[QQ * HSTR];   // bf16 Lam  [q][d]
    __shared__ __align__(16) ushort_t lhatH[QQ * HSTR];  // bf16 Lhat [q][d]
    __shared__ __align__(16) ushort_t smuH[QQ * HSTR];   // row0 = bf16 mu, rows1-15 zero
    __shared__ float sM[QQ * 17];
    __shared__ float sL[QQ * 17];
    __shared__ float sY[QQ * 17];    // L^-1
    __shared__ float sUvec[QQ];
    __shared__ float sPart[8];
    __shared__ float sScal[2];

    const int k = blockIdx.x;
    const int tid = threadIdx.x;
    const int lane = tid & 63;
    const int wave = tid >> 6;
    ushort_t* hb = (ushort_t*)(ws + OFF_HB);
    const int d = tid;   // exactly D threads

    float Psi  = expf(log_psi[k * DD + d]) + 1.1e-5f;  // exp+1e-6 then +1e-5 jitter
    float vinv = 1.0f / Psi;
    float mud  = mu[k * DD + d];
    float wv   = vinv * mud;
    hb[(512 + k) * DD + d] = f2bf(vinv);   // V row
    hb[(544 + k) * DD + d] = f2bf(wv);     // W row
    smuH[d] = f2bf(mud);                   // mu row 0
    float logPsi = logf(Psi);
    float ckp = wv * mud;

    // load Lambda row d (16 floats, kept fp32 in registers), bf16 Lam/Lhat to LDS
    float lam[QQ];
    {
        const float4* lrow = reinterpret_cast<const float4*>(Lambda + (size_t)(k * DD + d) * QQ);
#pragma unroll
        for (int i = 0; i < 4; ++i) {
            float4 t = lrow[i];
            lam[4 * i + 0] = t.x; lam[4 * i + 1] = t.y;
            lam[4 * i + 2] = t.z; lam[4 * i + 3] = t.w;
        }
#pragma unroll
        for (int q = 0; q < QQ; ++q) {
            lamH[q * HSTR + d]  = f2bf(lam[q]);
            lhatH[q * HSTR + d] = f2bf(lam[q] * vinv);
        }
    }
    // zero smuH rows 1-15 (990 ushort4)
#pragma unroll
    for (int i = 0; i < 4; ++i) {
        int idx = tid + i * 256;
        if (idx < 990)
            *reinterpret_cast<ushort4*>(smuH + HSTR + idx * 4) = make_ushort4(0, 0, 0, 0);
    }

    // block reduce sum(logPsi), sum(v*mu^2)
    float r0 = logPsi, r1 = ckp;
#pragma unroll
    for (int off = 32; off >= 1; off >>= 1) {
        r0 += __shfl_down(r0, off);
        r1 += __shfl_down(r1, off);
    }
    if ((tid & 63) == 0) { sPart[wave] = r0; sPart[4 + wave] = r1; }
    __syncthreads();                                            // B1 (fences staging too)
    if (tid == 0) {
        sScal[0] = sPart[0] + sPart[1] + sPart[2] + sPart[3];
        sScal[1] = sPart[4] + sPart[5] + sPart[6] + sPart[7];
    }

    // ---- wave 0 only: MFMA M,u -> Cholesky -> Y=L^-1 -> u2 ----
    if (wave == 0) {
        const int arow = lane & 15;
        const int quad = lane >> 4;
        const ushort_t* pa = lhatH + arow * HSTR + quad * 8;
        const ushort_t* pl = lamH  + arow * HSTR + quad * 8;
        const ushort_t* pm = smuH  + arow * HSTR + quad * 8;
        f32x4 accM = (f32x4){0.f, 0.f, 0.f, 0.f};
        f32x4 accU = (f32x4){0.f, 0.f, 0.f, 0.f};
#pragma unroll
        for (int ks = 0; ks < 8; ++ks) {
            short8 a = *reinterpret_cast<const short8*>(pa + ks * 32);
            accM = __builtin_amdgcn_mfma_f32_16x16x32_bf16(
                a, *reinterpret_cast<const short8*>(pl + ks * 32), accM, 0, 0, 0);
            accU = __builtin_amdgcn_mfma_f32_16x16x32_bf16(
                a, *reinterpret_cast<const short8*>(pm + ks * 32), accU, 0, 0, 0);
        }
        // C layout: col=lane&15 (-> r), row=quad*4+reg (-> q)
#pragma unroll
        for (int reg = 0; reg < 4; ++reg) {
            int q = quad * 4 + reg;
            sM[q * 17 + arow] = accM[reg] + ((q == arow) ? 1.0f : 0.0f);
        }
        if (arow == 0) {
#pragma unroll
            for (int reg = 0; reg < 4; ++reg)
                sUvec[quad * 4 + reg] = accU[reg];   // u[q]
        }

        // Cholesky (lanes 0..15), column broadcast via sL slot 16
        if (lane < QQ) {
            const int r = lane;
            float m[QQ], l[QQ];
#pragma unroll
            for (int c = 0; c < QQ; ++c) m[c] = sM[r * 17 + c];
#pragma unroll
            for (int j = 0; j < QQ; ++j) {
                float djj = __shfl(m[j], j);
                float rinv = 1.0f / sqrtf(djj);
                l[j] = m[j] * rinv;
                sL[r * 17 + 16] = l[j];          // publish column j
#pragma unroll
                for (int c = 0; c < QQ; ++c)
                    if (c > j) m[c] -= l[j] * sL[c * 17 + 16];
            }
#pragma unroll
            for (int j = 0; j < QQ; ++j) sL[r * 17 + j] = l[j];
            float dl = logf(l[r]);
            dl += __shfl_xor(dl, 1); dl += __shfl_xor(dl, 2);
            dl += __shfl_xor(dl, 4); dl += __shfl_xor(dl, 8);
            if (r == 0) sPart[1] = dl;   // logdetL

            // Y = L^-1, column per lane: sY[j*17+c] = Linv[j][c]
            float y[QQ];
#pragma unroll
            for (int j = 0; j < QQ; ++j) {
                float acc = (j == r) ? 1.0f : 0.0f;
#pragma unroll
                for (int i = 0; i < QQ; ++i)
                    if (i < j) acc -= sL[j * 17 + i] * y[i];
                y[j] = acc / sL[j * 17 + j];
            }
#pragma unroll
            for (int j = 0; j < QQ; ++j) sY[j * 17 + r] = y[j];

            // u2 = L^-1 u : u2[r] = sum_i Linv[r][i] * u[i]
            float u2 = 0.f;
#pragma unroll
            for (int i = 0; i < QQ; ++i)
                u2 += sY[r * 17 + i] * sUvec[i];
            ws[OFF_U + k * QQ + r] = u2;
        }
    }
    __syncthreads();                                            // B2

    // Lhat2 = Lhat . L^-T : row d, all 256 threads; panel write (bf16, once)
    {
#pragma unroll
        for (int q = 0; q < QQ; ++q) {
            float acc = 0.f;
#pragma unroll
            for (int j = 0; j < QQ; ++j)
                acc += lam[j] * sY[q * 17 + j];     // Linv[q][j]
            hb[(k * QQ + q) * DD + d] = f2bf(vinv * acc);
        }
    }
    if (tid == 0) {
        float logdet = sScal[0] + 2.0f * sPart[1];  // sum log Psi + logdet M
        ws[OFF_LOGC + k] = log_pi[k] - 0.5f * ((float)DD * LOG2PI_F + logdet)
                         - 0.5f * sScal[1];         // fold ck in
    }
}

// ---------------- Kernel 2: single-barrier MFMA + corr + fused lse -----------
// grid 256 blocks x 512 threads, 16 rows x all 32 comps. A-frags loaded
// DIRECTLY from global (layout A[m=lane&15][k=quad*8+j] = 8 contiguous floats
// per ks) -> no X staging, no first barrier.
#define QSTR 68   // qx/sx row stride (floats)
#define CSTR 36   // corr row stride (floats)

__global__ __launch_bounds__(512, 2) void main_kernel(
    const float* __restrict__ X, const float* __restrict__ ws,
    float* __restrict__ out)
{
    const int tid  = threadIdx.x;
    const int lane = tid & 63;
    const int wave = tid >> 6;         // 0..7
    const int n0   = blockIdx.x * NROW;
    const ushort_t* hB = (const ushort_t*)(ws + OFF_HB);

    __shared__ __align__(16) float sQS[NROW * QSTR];  // qx (0-31), sx (32-63)
    __shared__ __align__(16) float sCorr[NROW * CSTR];
    __shared__ float sLogc[KC];

    if (tid < KC) sLogc[tid] = ws[OFF_LOGC + tid];    // visible after B2

    const int arow = lane & 15;
    const int quad = lane >> 4;

    // ---- A-frags direct from global: row n0+arow, k = ks*32 + quad*8 + j ----
    short8 a[8];
    {
        const float* xrow = X + (size_t)(n0 + arow) * DD + quad * 8;
#pragma unroll
        for (int ks = 0; ks < 8; ++ks) {
            float4 v0 = *reinterpret_cast<const float4*>(xrow + ks * 32);
            float4 v1 = *reinterpret_cast<const float4*>(xrow + ks * 32 + 4);
            short8 t;
            t[0] = (short)f2bf(v0.x); t[1] = (short)f2bf(v0.y);
            t[2] = (short)f2bf(v0.z); t[3] = (short)f2bf(v0.w);
            t[4] = (short)f2bf(v1.x); t[5] = (short)f2bf(v1.y);
            t[6] = (short)f2bf(v1.z); t[7] = (short)f2bf(v1.w);
            a[ks] = t;
        }
    }

    // ---- MFMA over 4 Lhat2 tiles (2 passes of 2) + special qx/sx tiles ----
    {
#pragma unroll
        for (int pass = 0; pass < 2; ++pass) {
            short8 b[2][8];
            float  uu[2];
#pragma unroll
            for (int i = 0; i < 2; ++i) {
                const int tile = wave * 4 + pass * 2 + i;
                const ushort_t* gB = hB + (size_t)(tile * 16 + arow) * DD + quad * 8;
#pragma unroll
                for (int ks = 0; ks < 8; ++ks)
                    b[i][ks] = *reinterpret_cast<const short8*>(gB + ks * 32);
                uu[i] = ws[OFF_U + tile * 16 + arow];   // u2[comp=tile][q=arow]
            }
            f32x4 acc[2];
#pragma unroll
            for (int i = 0; i < 2; ++i) acc[i] = (f32x4){0.f, 0.f, 0.f, 0.f};
#pragma unroll
            for (int ks = 0; ks < 8; ++ks)
#pragma unroll
                for (int i = 0; i < 2; ++i)
                    acc[i] = __builtin_amdgcn_mfma_f32_16x16x32_bf16(a[ks], b[i][ks], acc[i], 0, 0, 0);
#pragma unroll
            for (int i = 0; i < 2; ++i) {
                const int tile = wave * 4 + pass * 2 + i;
                float s0 = acc[i][0] - uu[i], s1 = acc[i][1] - uu[i],
                      s2 = acc[i][2] - uu[i], s3 = acc[i][3] - uu[i];
                s0 *= s0; s1 *= s1; s2 *= s2; s3 *= s3;
                // butterfly over the 16 arow-lanes (masks 1,2,4,8 stay in-quad)
#pragma unroll
                for (int mask = 1; mask < 16; mask <<= 1) {
                    s0 += __shfl_xor(s0, mask);
                    s1 += __shfl_xor(s1, mask);
                    s2 += __shfl_xor(s2, mask);
                    s3 += __shfl_xor(s3, mask);
                }
                if (arow == 0) {
                    sCorr[(quad * 4 + 0) * CSTR + tile] = s0;
                    sCorr[(quad * 4 + 1) * CSTR + tile] = s1;
                    sCorr[(quad * 4 + 2) * CSTR + tile] = s2;
                    sCorr[(quad * 4 + 3) * CSTR + tile] = s3;
                }
            }
        }
        if (wave < 4) {
            short8 aa[8];
            if (wave < 2) {   // A = X^2 (bf16) for qx tiles
#pragma unroll
                for (int ks = 0; ks < 8; ++ks) {
                    short8 sq;
#pragma unroll
                    for (int e = 0; e < 8; ++e) {
                        float xf = bf2f((ushort_t)a[ks][e]);
                        sq[e] = (short)f2bf(xf * xf);
                    }
                    aa[ks] = sq;
                }
            } else {
#pragma unroll
                for (int ks = 0; ks < 8; ++ks) aa[ks] = a[ks];
            }
            const ushort_t* gB = hB + (size_t)(512 + wave * 16 + arow) * DD + quad * 8;
            f32x4 accs = (f32x4){0.f, 0.f, 0.f, 0.f};
#pragma unroll
            for (int ks = 0; ks < 8; ++ks)
                accs = __builtin_amdgcn_mfma_f32_16x16x32_bf16(
                    aa[ks], *reinterpret_cast<const short8*>(gB + ks * 32), accs, 0, 0, 0);
            const int col = (wave & 1) * 16 + arow + ((wave >> 1) & 1) * 32;
#pragma unroll
            for (int r = 0; r < 4; ++r)
                sQS[(quad * 4 + r) * QSTR + col] = accs[r];
        }
    }
    __syncthreads();                                            // B2 (only barrier)

    // ---- combine + logsumexp + store: row's 32 comps = 32 consecutive lanes ----
    {
        const int row = tid >> 5;          // 0..15
        const int c   = tid & 31;          // comp
        float qx   = sQS[row * QSTR + c];
        float sx   = sQS[row * QSTR + 32 + c];
        float corr = sCorr[row * CSTR + c];
        float val  = sLogc[c] - 0.5f * (qx - 2.0f * sx - corr);

        // 32-lane aligned group: masks 1..16 stay inside the group
        float m = val;
#pragma unroll
        for (int mask = 1; mask < 32; mask <<= 1)
            m = fmaxf(m, __shfl_xor(m, mask));
        float e = expf(val - m);
        float s = e;
#pragma unroll
        for (int mask = 1; mask < 32; mask <<= 1)
            s += __shfl_xor(s, mask);
        float lse = m + logf(s);

        out[(size_t)(n0 + row) * KC + c] = val - lse;
        if (c == 0) out[(size_t)NPTS * KC + n0 + row] = lse;
    }
}

extern "C" void kernel_launch(void* const* d_in, const int* in_sizes, int n_in,
                              void* d_out, int out_size, void* d_ws, size_t ws_size,
                              hipStream_t stream)
{
    (void)in_sizes; (void)n_in; (void)out_size; (void)ws_size;
    const float* X       = (const float*)d_in[0];
    const float* log_pi  = (const float*)d_in[1];
    const float* mu      = (const float*)d_in[2];
    const float* Lambda  = (const float*)d_in[3];
    const float* log_psi = (const float*)d_in[4];
    float* out = (float*)d_out;
    float* ws  = (float*)d_ws;   // ~290 KB used

    precompute_kernel<<<dim3(KC), dim3(256), 0, stream>>>(log_pi, mu, Lambda, log_psi, ws);
    main_kernel<<<dim3(NPTS / NROW), dim3(512), 0, stream>>>(X, ws, out);
}

// Round 14
// 80.936 us; speedup vs baseline: 1.0367x; 1.0367x over previous
//
#include <hip/hip_runtime.h>
#include <math.h>

#define KC 32      // components
#define DD 256     // dims
#define QQ 16      // rank
#define NPTS 4096
#define NROW 16    // rows per main block
#define LOG2PI_F 1.8378770664093453f

typedef unsigned short ushort_t;

// ws layout (float offsets)
#define OFF_U    0      // [512] u2 = L^-1 (Lhat . mu)   (rotated)
#define OFF_LOGC 512    // [32]  log_pi - 0.5*(D*log2pi + logdetC + ck)
#define OFF_HB   544    // ushort [576][256] bf16 panel:
                        //   rows   0-511: Lhat2 = Psi^-1 Lam L^-T (comp k, rank q) at k*16+q
                        //   rows 512-543: V  = psi_inv (comp c at 512+c)
                        //   rows 544-575: W  = psi_inv*mu

__device__ __forceinline__ ushort_t f2bf(float f) {
    union { float f; unsigned int u; } c; c.f = f;
    unsigned int u = c.u;
    return (ushort_t)((u + 0x7FFFu + ((u >> 16) & 1u)) >> 16);   // RNE
}
__device__ __forceinline__ float bf2f(ushort_t h) {
    union { unsigned int u; float f; } c; c.u = ((unsigned int)h) << 16;
    return c.f;
}

using short8 = __attribute__((ext_vector_type(8))) short;   // 8 bf16 (4 VGPRs)
using f32x4  = __attribute__((ext_vector_type(4))) float;   // 4 fp32 acc

// ---------------- Kernel 1: per-component precompute (32 blocks x 256 thr) ----
// M,u via wave-0 MFMA; Cholesky M=LL^T; panel stores Lhat2 = Lhat L^-T, u2 = L^-1 u.
#define HSTR 264   // bf16 LDS row stride (ushorts)
__global__ __launch_bounds__(256) void precompute_kernel(
    const float* __restrict__ log_pi, const float* __restrict__ mu,
    const float* __restrict__ Lambda, const float* __restrict__ log_psi,
    float* __restrict__ ws)
{
    __shared__ __align__(16) ushort_t lamH[QQ * HSTR];   // bf16 Lam  [q][d]
    __shared__ __align__(16) ushort_t lhatH[QQ * HSTR];  // bf16 Lhat [q][d]
    __shared__ __align__(16) ushort_t smuH[QQ * HSTR];   // row0 = bf16 mu, rows1-15 zero
    __shared__ float sM[QQ * 17];
    __shared__ float sL[QQ * 17];
    __shared__ float sY[QQ * 17];    // L^-1
    __shared__ float sUvec[QQ];
    __shared__ float sPart[8];
    __shared__ float sScal[2];

    const int k = blockIdx.x;
    const int tid = threadIdx.x;
    const int lane = tid & 63;
    const int wave = tid >> 6;
    ushort_t* hb = (ushort_t*)(ws + OFF_HB);
    const int d = tid;   // exactly D threads

    float Psi  = expf(log_psi[k * DD + d]) + 1.1e-5f;  // exp+1e-6 then +1e-5 jitter
    float vinv = 1.0f / Psi;
    float mud  = mu[k * DD + d];
    float wv   = vinv * mud;
    hb[(512 + k) * DD + d] = f2bf(vinv);   // V row
    hb[(544 + k) * DD + d] = f2bf(wv);     // W row
    smuH[d] = f2bf(mud);                   // mu row 0
    float logPsi = logf(Psi);
    float ckp = wv * mud;

    // load Lambda row d (16 floats, kept fp32 in registers), bf16 Lam/Lhat to LDS
    float lam[QQ];
    {
        const float4* lrow = reinterpret_cast<const float4*>(Lambda + (size_t)(k * DD + d) * QQ);
#pragma unroll
        for (int i = 0; i < 4; ++i) {
            float4 t = lrow[i];
            lam[4 * i + 0] = t.x; lam[4 * i + 1] = t.y;
            lam[4 * i + 2] = t.z; lam[4 * i + 3] = t.w;
        }
#pragma unroll
        for (int q = 0; q < QQ; ++q) {
            lamH[q * HSTR + d]  = f2bf(lam[q]);
            lhatH[q * HSTR + d] = f2bf(lam[q] * vinv);
        }
    }
    // zero smuH rows 1-15 (990 ushort4)
#pragma unroll
    for (int i = 0; i < 4; ++i) {
        int idx = tid + i * 256;
        if (idx < 990)
            *reinterpret_cast<ushort4*>(smuH + HSTR + idx * 4) = make_ushort4(0, 0, 0, 0);
    }

    // block reduce sum(logPsi), sum(v*mu^2)
    float r0 = logPsi, r1 = ckp;
#pragma unroll
    for (int off = 32; off >= 1; off >>= 1) {
        r0 += __shfl_down(r0, off);
        r1 += __shfl_down(r1, off);
    }
    if ((tid & 63) == 0) { sPart[wave] = r0; sPart[4 + wave] = r1; }
    __syncthreads();                                            // B1 (fences staging too)
    if (tid == 0) {
        sScal[0] = sPart[0] + sPart[1] + sPart[2] + sPart[3];
        sScal[1] = sPart[4] + sPart[5] + sPart[6] + sPart[7];
    }

    // ---- wave 0 only: MFMA M,u -> Cholesky -> Y=L^-1 -> u2 ----
    if (wave == 0) {
        const int arow = lane & 15;
        const int quad = lane >> 4;
        const ushort_t* pa = lhatH + arow * HSTR + quad * 8;
        const ushort_t* pl = lamH  + arow * HSTR + quad * 8;
        const ushort_t* pm = smuH  + arow * HSTR + quad * 8;
        f32x4 accM = (f32x4){0.f, 0.f, 0.f, 0.f};
        f32x4 accU = (f32x4){0.f, 0.f, 0.f, 0.f};
#pragma unroll
        for (int ks = 0; ks < 8; ++ks) {
            short8 a = *reinterpret_cast<const short8*>(pa + ks * 32);
            accM = __builtin_amdgcn_mfma_f32_16x16x32_bf16(
                a, *reinterpret_cast<const short8*>(pl + ks * 32), accM, 0, 0, 0);
            accU = __builtin_amdgcn_mfma_f32_16x16x32_bf16(
                a, *reinterpret_cast<const short8*>(pm + ks * 32), accU, 0, 0, 0);
        }
        // C layout: col=lane&15 (-> r), row=quad*4+reg (-> q)
#pragma unroll
        for (int reg = 0; reg < 4; ++reg) {
            int q = quad * 4 + reg;
            sM[q * 17 + arow] = accM[reg] + ((q == arow) ? 1.0f : 0.0f);
        }
        if (arow == 0) {
#pragma unroll
            for (int reg = 0; reg < 4; ++reg)
                sUvec[quad * 4 + reg] = accU[reg];   // u[q]
        }

        // Cholesky (lanes 0..15), column broadcast via sL slot 16
        if (lane < QQ) {
            const int r = lane;
            float m[QQ], l[QQ];
#pragma unroll
            for (int c = 0; c < QQ; ++c) m[c] = sM[r * 17 + c];
#pragma unroll
            for (int j = 0; j < QQ; ++j) {
                float djj = __shfl(m[j], j);
                float rinv = 1.0f / sqrtf(djj);
                l[j] = m[j] * rinv;
                sL[r * 17 + 16] = l[j];          // publish column j
#pragma unroll
                for (int c = 0; c < QQ; ++c)
                    if (c > j) m[c] -= l[j] * sL[c * 17 + 16];
            }
#pragma unroll
            for (int j = 0; j < QQ; ++j) sL[r * 17 + j] = l[j];
            float dl = logf(l[r]);
            dl += __shfl_xor(dl, 1); dl += __shfl_xor(dl, 2);
            dl += __shfl_xor(dl, 4); dl += __shfl_xor(dl, 8);
            if (r == 0) sPart[1] = dl;   // logdetL

            // Y = L^-1, column per lane: sY[j*17+c] = Linv[j][c]
            float y[QQ];
#pragma unroll
            for (int j = 0; j < QQ; ++j) {
                float acc = (j == r) ? 1.0f : 0.0f;
#pragma unroll
                for (int i = 0; i < QQ; ++i)
                    if (i < j) acc -= sL[j * 17 + i] * y[i];
                y[j] = acc / sL[j * 17 + j];
            }
#pragma unroll
            for (int j = 0; j < QQ; ++j) sY[j * 17 + r] = y[j];

            // u2 = L^-1 u : u2[r] = sum_i Linv[r][i] * u[i]
            float u2 = 0.f;
#pragma unroll
            for (int i = 0; i < QQ; ++i)
                u2 += sY[r * 17 + i] * sUvec[i];
            ws[OFF_U + k * QQ + r] = u2;
        }
    }
    __syncthreads();                                            // B2

    // Lhat2 = Lhat . L^-T : row d, all 256 threads; panel write (bf16, once)
    {
#pragma unroll
        for (int q = 0; q < QQ; ++q) {
            float acc = 0.f;
#pragma unroll
            for (int j = 0; j < QQ; ++j)
                acc += lam[j] * sY[q * 17 + j];     // Linv[q][j]
            hb[(k * QQ + q) * DD + d] = f2bf(vinv * acc);
        }
    }
    if (tid == 0) {
        float logdet = sScal[0] + 2.0f * sPart[1];  // sum log Psi + logdet M
        ws[OFF_LOGC + k] = log_pi[k] - 0.5f * ((float)DD * LOG2PI_F + logdet)
                         - 0.5f * sScal[1];         // fold ck in
    }
}

// ---------------- Kernel 2: MFMA GEMM + in-register corr + fused lse ---------
// grid 256 blocks x 512 threads, 16 rows x all 32 comps. Only 2 barriers:
// stage -> MFMA(writes sQS/sCorr) -> combine+logsumexp+store (32-lane butterfly).
#define SXH 264   // bf16 X row stride (ushorts)
#define QSTR 68   // qx/sx row stride (floats)
#define CSTR 36   // corr row stride (floats)

__global__ __launch_bounds__(512, 2) void main_kernel(
    const float* __restrict__ X, const float* __restrict__ ws,
    float* __restrict__ out)
{
    const int tid  = threadIdx.x;
    const int lane = tid & 63;
    const int wave = tid >> 6;         // 0..7
    const int n0   = blockIdx.x * NROW;
    const ushort_t* hB = (const ushort_t*)(ws + OFF_HB);

    __shared__ __align__(16) ushort_t xh[NROW * SXH];
    __shared__ __align__(16) float    sQS[NROW * QSTR];  // qx (0-31), sx (32-63)
    __shared__ __align__(16) float    sCorr[NROW * CSTR];
    __shared__ float sU[512];
    __shared__ float sLogc[KC];

    // ---- staging: X rows as bf16 + u2 + logc ----
    {
        const float4* gx = reinterpret_cast<const float4*>(X + (size_t)n0 * DD);
#pragma unroll
        for (int i = 0; i < 2; ++i) {
            int f = tid + i * 512;
            int row = f >> 6, d4 = f & 63;
            float4 v = gx[f];
            *reinterpret_cast<ushort4*>(&xh[row * SXH + d4 * 4]) =
                make_ushort4(f2bf(v.x), f2bf(v.y), f2bf(v.z), f2bf(v.w));
        }
        sU[tid] = ws[OFF_U + tid];
        if (tid < KC) sLogc[tid] = ws[OFF_LOGC + tid];
    }
    __syncthreads();                                            // B1

    // ---- MFMA over 4 Lhat2 tiles (2 passes of 2) + special qx/sx tiles ----
    {
        const int arow = lane & 15;
        const int quad = lane >> 4;
        short8 a[8];
        const ushort_t* ab = xh + arow * SXH + quad * 8;
#pragma unroll
        for (int ks = 0; ks < 8; ++ks) a[ks] = *reinterpret_cast<const short8*>(ab + ks * 32);

#pragma unroll
        for (int pass = 0; pass < 2; ++pass) {
            short8 b[2][8];
#pragma unroll
            for (int i = 0; i < 2; ++i) {
                const int tile = wave * 4 + pass * 2 + i;
                const ushort_t* gB = hB + (size_t)(tile * 16 + arow) * DD + quad * 8;
#pragma unroll
                for (int ks = 0; ks < 8; ++ks)
                    b[i][ks] = *reinterpret_cast<const short8*>(gB + ks * 32);
            }
            f32x4 acc[2];
#pragma unroll
            for (int i = 0; i < 2; ++i) acc[i] = (f32x4){0.f, 0.f, 0.f, 0.f};
#pragma unroll
            for (int ks = 0; ks < 8; ++ks)
#pragma unroll
                for (int i = 0; i < 2; ++i)
                    acc[i] = __builtin_amdgcn_mfma_f32_16x16x32_bf16(a[ks], b[i][ks], acc[i], 0, 0, 0);
#pragma unroll
            for (int i = 0; i < 2; ++i) {
                const int tile = wave * 4 + pass * 2 + i;
                float uu = sU[tile * 16 + arow];     // u2[comp=tile][q=arow]
                float s0 = acc[i][0] - uu, s1 = acc[i][1] - uu,
                      s2 = acc[i][2] - uu, s3 = acc[i][3] - uu;
                s0 *= s0; s1 *= s1; s2 *= s2; s3 *= s3;
                // butterfly over the 16 arow-lanes (masks 1,2,4,8 stay in-quad)
#pragma unroll
                for (int mask = 1; mask < 16; mask <<= 1) {
                    s0 += __shfl_xor(s0, mask);
                    s1 += __shfl_xor(s1, mask);
                    s2 += __shfl_xor(s2, mask);
                    s3 += __shfl_xor(s3, mask);
                }
                if (arow == 0) {
                    sCorr[(quad * 4 + 0) * CSTR + tile] = s0;
                    sCorr[(quad * 4 + 1) * CSTR + tile] = s1;
                    sCorr[(quad * 4 + 2) * CSTR + tile] = s2;
                    sCorr[(quad * 4 + 3) * CSTR + tile] = s3;
                }
            }
        }
        if (wave < 4) {
            short8 aa[8];
            if (wave < 2) {   // A = X^2 (bf16) for qx tiles
#pragma unroll
                for (int ks = 0; ks < 8; ++ks) {
                    short8 sq;
#pragma unroll
                    for (int e = 0; e < 8; ++e) {
                        float xf = bf2f((ushort_t)a[ks][e]);
                        sq[e] = (short)f2bf(xf * xf);
                    }
                    aa[ks] = sq;
                }
            } else {
#pragma unroll
                for (int ks = 0; ks < 8; ++ks) aa[ks] = a[ks];
            }
            const ushort_t* gB = hB + (size_t)(512 + wave * 16 + arow) * DD + quad * 8;
            f32x4 accs = (f32x4){0.f, 0.f, 0.f, 0.f};
#pragma unroll
            for (int ks = 0; ks < 8; ++ks)
                accs = __builtin_amdgcn_mfma_f32_16x16x32_bf16(
                    aa[ks], *reinterpret_cast<const short8*>(gB + ks * 32), accs, 0, 0, 0);
            const int col = (wave & 1) * 16 + arow + ((wave >> 1) & 1) * 32;
#pragma unroll
            for (int r = 0; r < 4; ++r)
                sQS[(quad * 4 + r) * QSTR + col] = accs[r];
        }
    }
    __syncthreads();                                            // B2

    // ---- combine + logsumexp + store: row's 32 comps = 32 consecutive lanes ----
    {
        const int row = tid >> 5;          // 0..15
        const int c   = tid & 31;          // comp
        float qx   = sQS[row * QSTR + c];
        float sx   = sQS[row * QSTR + 32 + c];
        float corr = sCorr[row * CSTR + c];
        float val  = sLogc[c] - 0.5f * (qx - 2.0f * sx - corr);

        // 32-lane aligned group: masks 1..16 stay inside the group
        float m = val;
#pragma unroll
        for (int mask = 1; mask < 32; mask <<= 1)
            m = fmaxf(m, __shfl_xor(m, mask));
        float e = expf(val - m);
        float s = e;
#pragma unroll
        for (int mask = 1; mask < 32; mask <<= 1)
            s += __shfl_xor(s, mask);
        float lse = m + logf(s);

        out[(size_t)(n0 + row) * KC + c] = val - lse;
        if (c == 0) out[(size_t)NPTS * KC + n0 + row] = lse;
    }
}

extern "C" void kernel_launch(void* const* d_in, const int* in_sizes, int n_in,
                              void* d_out, int out_size, void* d_ws, size_t ws_size,
                              hipStream_t stream)
{
    (void)in_sizes; (void)n_in; (void)out_size; (void)ws_size;
    const float* X       = (const float*)d_in[0];
    const float* log_pi  = (const float*)d_in[1];
    const float* mu      = (const float*)d_in[2];
    const float* Lambda  = (const float*)d_in[3];
    const float* log_psi = (const float*)d_in[4];
    float* out = (float*)d_out;
    float* ws  = (float*)d_ws;   // ~290 KB used

    precompute_kernel<<<dim3(KC), dim3(256), 0, stream>>>(log_pi, mu, Lambda, log_psi, ws);
    main_kernel<<<dim3(NPTS / NROW), dim3(512), 0, stream>>>(X, ws, out);
}